// Round 1
// baseline (65.461 us; speedup 1.0000x reference)
//
#include <hip/hip_runtime.h>
#include <stdint.h>

#define T_DIM 8192
#define J_DIM 1024
#define D_DIM 256

typedef __bf16 bf16x8 __attribute__((ext_vector_type(8)));
typedef float f32x4 __attribute__((ext_vector_type(4)));
typedef unsigned short u16x8 __attribute__((ext_vector_type(8)));
typedef unsigned short u16x4 __attribute__((ext_vector_type(4)));

__device__ inline unsigned short f2bf(float x) {
    unsigned u = __builtin_bit_cast(unsigned, x);
    u += 0x7FFFu + ((u >> 16) & 1u);
    return (unsigned short)(u >> 16);
}
__device__ inline float bf2f(unsigned short h) {
    return __builtin_bit_cast(float, ((unsigned)h) << 16);
}

// K0a: Cm = bf16(context * w_m), cw[t] = context[t,:] . w_c
__global__ __launch_bounds__(256) void prep_ctx(const float* __restrict__ ctx,
                                                const float* __restrict__ w,
                                                unsigned short* __restrict__ Cm,
                                                float* __restrict__ cw) {
    int wid = threadIdx.x >> 6, lane = threadIdx.x & 63;
    int t = blockIdx.x * 4 + wid;
    float4 c  = *(const float4*)(ctx + (size_t)t * D_DIM + lane * 4);
    float4 wm = *(const float4*)(w + 2 * D_DIM + lane * 4);
    float4 wc = *(const float4*)(w + lane * 4);
    u16x4 cmv;
    cmv[0] = f2bf(c.x * wm.x);
    cmv[1] = f2bf(c.y * wm.y);
    cmv[2] = f2bf(c.z * wm.z);
    cmv[3] = f2bf(c.w * wm.w);
    *(u16x4*)(Cm + (size_t)t * D_DIM + lane * 4) = cmv;
    float s = c.x * wc.x + c.y * wc.y + c.z * wc.z + c.w * wc.w;
    #pragma unroll
    for (int o = 1; o < 64; o <<= 1) s += __shfl_xor(s, o);
    if (lane == 0) cw[t] = s;
}

// K0b: Qb = bf16(query) row-major, QT = bf16(query) transposed [d][j], qw[j] = query[j,:] . w_q
__global__ __launch_bounds__(256) void prep_q(const float* __restrict__ qry,
                                              const float* __restrict__ w,
                                              unsigned short* __restrict__ Qb,
                                              unsigned short* __restrict__ QT,
                                              float* __restrict__ qw) {
    int wid = threadIdx.x >> 6, lane = threadIdx.x & 63;
    int j = blockIdx.x * 4 + wid;
    float4 c  = *(const float4*)(qry + (size_t)j * D_DIM + lane * 4);
    float4 wq = *(const float4*)(w + D_DIM + lane * 4);
    u16x4 qv;
    qv[0] = f2bf(c.x);
    qv[1] = f2bf(c.y);
    qv[2] = f2bf(c.z);
    qv[3] = f2bf(c.w);
    *(u16x4*)(Qb + (size_t)j * D_DIM + lane * 4) = qv;
    int d0 = lane * 4;
    QT[(size_t)(d0 + 0) * J_DIM + j] = qv[0];
    QT[(size_t)(d0 + 1) * J_DIM + j] = qv[1];
    QT[(size_t)(d0 + 2) * J_DIM + j] = qv[2];
    QT[(size_t)(d0 + 3) * J_DIM + j] = qv[3];
    float s = c.x * wq.x + c.y * wq.y + c.z * wq.z + c.w * wq.w;
    #pragma unroll
    for (int o = 1; o < 64; o <<= 1) s += __shfl_xor(s, o);
    if (lane == 0) qw[j] = s;
}

// K1: P[t][j] = bf16( exp( Cm[t,:] . Qb[j,:] + qw[j] ) )
// 128x128 tile, BK=64, 4 waves (2x2), each wave 64x64 = 4x4 16x16 frags.
__global__ __launch_bounds__(256) void gemm_s(const unsigned short* __restrict__ Cm,
                                              const unsigned short* __restrict__ Qb,
                                              const float* __restrict__ qw,
                                              unsigned short* __restrict__ P) {
    __shared__ unsigned short As[128 * 64];
    __shared__ unsigned short Bs[128 * 64];
    int tid = threadIdx.x;
    int lane = tid & 63, wv = tid >> 6;
    int wm = wv >> 1, wn = wv & 1;
    int bm = blockIdx.x, bn = blockIdx.y;
    f32x4 acc[4][4] = {};

    for (int k0 = 0; k0 < 256; k0 += 64) {
        if (k0) __syncthreads();
        #pragma unroll
        for (int i = 0; i < 4; ++i) {
            int cid = tid + i * 256;           // chunk id, 8 bf16 per chunk
            int r = cid >> 3, cc = cid & 7;
            u16x8 av = *(const u16x8*)(Cm + (size_t)(bm * 128 + r) * 256 + k0 + cc * 8);
            *(u16x8*)(As + r * 64 + ((cc ^ (r & 7)) << 3)) = av;
            u16x8 bv = *(const u16x8*)(Qb + (size_t)(bn * 128 + r) * 256 + k0 + cc * 8);
            *(u16x8*)(Bs + r * 64 + ((cc ^ (r & 7)) << 3)) = bv;
        }
        __syncthreads();
        #pragma unroll
        for (int ks = 0; ks < 2; ++ks) {
            int klo = (lane >> 4) + ks * 4;    // chunk index along k
            bf16x8 af[4], bfr[4];
            #pragma unroll
            for (int f = 0; f < 4; ++f) {
                int ra = wm * 64 + f * 16 + (lane & 15);
                af[f] = __builtin_bit_cast(bf16x8,
                        *(const u16x8*)(As + ra * 64 + ((klo ^ (ra & 7)) << 3)));
                int rb = wn * 64 + f * 16 + (lane & 15);
                bfr[f] = __builtin_bit_cast(bf16x8,
                        *(const u16x8*)(Bs + rb * 64 + ((klo ^ (rb & 7)) << 3)));
            }
            #pragma unroll
            for (int m = 0; m < 4; ++m)
                #pragma unroll
                for (int n = 0; n < 4; ++n)
                    acc[m][n] = __builtin_amdgcn_mfma_f32_16x16x32_bf16(af[m], bfr[n], acc[m][n], 0, 0, 0);
        }
    }

    int rgrp = lane >> 4, cidx = lane & 15;
    #pragma unroll
    for (int n = 0; n < 4; ++n) {
        int j = bn * 128 + wn * 64 + n * 16 + cidx;
        float qwv = qw[j];
        #pragma unroll
        for (int m = 0; m < 4; ++m) {
            int tb = bm * 128 + wm * 64 + m * 16 + rgrp * 4;
            #pragma unroll
            for (int rg = 0; rg < 4; ++rg) {
                float s = acc[m][n][rg] + qwv;
                P[(size_t)(tb + rg) * J_DIM + j] = f2bf(__expf(s));
            }
        }
    }
}

// K2: per-row l = sum(P), b = log(max(P)) + cw; h_tilde[d] += sum_t b[t]*ctx[t][d]
__global__ __launch_bounds__(256) void rowstats(const unsigned short* __restrict__ P,
                                                const float* __restrict__ cw,
                                                const float* __restrict__ ctx,
                                                float* __restrict__ lsum,
                                                float* __restrict__ htilde) {
    __shared__ float bsh[16];
    int tid = threadIdx.x;
    int r = tid >> 4, q = tid & 15;
    int t = blockIdx.x * 16 + r;
    const unsigned short* Prow = P + (size_t)t * J_DIM;
    float sum = 0.f, mx = 0.f;
    #pragma unroll
    for (int i = 0; i < 8; ++i) {
        u16x8 v = *(const u16x8*)(Prow + q * 8 + i * 128);
        #pragma unroll
        for (int e = 0; e < 8; ++e) {
            float f = bf2f(v[e]);
            sum += f;
            mx = fmaxf(mx, f);
        }
    }
    #pragma unroll
    for (int o = 1; o < 16; o <<= 1) {
        sum += __shfl_xor(sum, o);
        mx = fmaxf(mx, __shfl_xor(mx, o));
    }
    if (q == 0) {
        lsum[t] = sum;
        bsh[r] = __logf(mx) + cw[t];
    }
    __syncthreads();
    float pb = 0.f;
    int d = tid;
    int tbase = blockIdx.x * 16;
    #pragma unroll
    for (int rr = 0; rr < 16; ++rr)
        pb += bsh[rr] * ctx[(size_t)(tbase + rr) * D_DIM + d];
    atomicAdd(htilde + d, pb);
}

// K3: acc = P @ query (via QT rows = B^T), epilogue writes all 4 G blocks.
// 128x64 tile, BK=64, 4 waves (2x2), each wave 64x32 = 4x2 frags.
__global__ __launch_bounds__(256) void gemm_o(const unsigned short* __restrict__ P,
                                              const unsigned short* __restrict__ QT,
                                              const float* __restrict__ lsum,
                                              const float* __restrict__ htilde,
                                              const float* __restrict__ ctx,
                                              float* __restrict__ G) {
    __shared__ unsigned short As[128 * 64];
    __shared__ unsigned short Bs[64 * 64];
    int tid = threadIdx.x;
    int lane = tid & 63, wv = tid >> 6;
    int wm = wv >> 1, wn = wv & 1;
    int bm = blockIdx.x, bn = blockIdx.y;
    f32x4 acc[4][2] = {};

    for (int k0 = 0; k0 < 1024; k0 += 64) {
        if (k0) __syncthreads();
        #pragma unroll
        for (int i = 0; i < 4; ++i) {
            int cid = tid + i * 256;
            int r = cid >> 3, cc = cid & 7;
            u16x8 av = *(const u16x8*)(P + (size_t)(bm * 128 + r) * J_DIM + k0 + cc * 8);
            *(u16x8*)(As + r * 64 + ((cc ^ (r & 7)) << 3)) = av;
        }
        #pragma unroll
        for (int i = 0; i < 2; ++i) {
            int cid = tid + i * 256;
            int r = cid >> 3, cc = cid & 7;    // r in 0..63
            u16x8 bv = *(const u16x8*)(QT + (size_t)(bn * 64 + r) * J_DIM + k0 + cc * 8);
            *(u16x8*)(Bs + r * 64 + ((cc ^ (r & 7)) << 3)) = bv;
        }
        __syncthreads();
        #pragma unroll
        for (int ks = 0; ks < 2; ++ks) {
            int klo = (lane >> 4) + ks * 4;
            bf16x8 af[4], bfr[2];
            #pragma unroll
            for (int f = 0; f < 4; ++f) {
                int ra = wm * 64 + f * 16 + (lane & 15);
                af[f] = __builtin_bit_cast(bf16x8,
                        *(const u16x8*)(As + ra * 64 + ((klo ^ (ra & 7)) << 3)));
            }
            #pragma unroll
            for (int f = 0; f < 2; ++f) {
                int rb = wn * 32 + f * 16 + (lane & 15);
                bfr[f] = __builtin_bit_cast(bf16x8,
                        *(const u16x8*)(Bs + rb * 64 + ((klo ^ (rb & 7)) << 3)));
            }
            #pragma unroll
            for (int m = 0; m < 4; ++m)
                #pragma unroll
                for (int n = 0; n < 2; ++n)
                    acc[m][n] = __builtin_amdgcn_mfma_f32_16x16x32_bf16(af[m], bfr[n], acc[m][n], 0, 0, 0);
        }
    }

    int rgrp = lane >> 4, cidx = lane & 15;
    #pragma unroll
    for (int m = 0; m < 4; ++m) {
        #pragma unroll
        for (int rg = 0; rg < 4; ++rg) {
            int t = bm * 128 + wm * 64 + m * 16 + rgrp * 4 + rg;
            float linv = 1.0f / lsum[t];
            float* gr = G + (size_t)t * 1024;
            #pragma unroll
            for (int n = 0; n < 2; ++n) {
                int d = bn * 64 + wn * 32 + n * 16 + cidx;
                float val = acc[m][n][rg] * linv;
                float c = ctx[(size_t)t * D_DIM + d];
                gr[d]       = c;
                gr[256 + d] = val;
                gr[512 + d] = c * val;
                gr[768 + d] = c * htilde[d];
            }
        }
    }
}

extern "C" void kernel_launch(void* const* d_in, const int* in_sizes, int n_in,
                              void* d_out, int out_size, void* d_ws, size_t ws_size,
                              hipStream_t stream) {
    (void)in_sizes; (void)n_in; (void)out_size; (void)ws_size;
    const float* ctx = (const float*)d_in[0];
    const float* qry = (const float*)d_in[1];
    const float* w   = (const float*)d_in[2];
    float* G = (float*)d_out;
    char* ws = (char*)d_ws;

    constexpr size_t OFF_P  = 0;                                   // 8192*1024*2 = 16 MiB
    constexpr size_t OFF_CM = OFF_P  + (size_t)T_DIM * J_DIM * 2;  // 8192*256*2  = 4 MiB
    constexpr size_t OFF_QB = OFF_CM + (size_t)T_DIM * D_DIM * 2;  // 1024*256*2
    constexpr size_t OFF_QT = OFF_QB + (size_t)J_DIM * D_DIM * 2;  // 256*1024*2
    constexpr size_t OFF_CW = OFF_QT + (size_t)D_DIM * J_DIM * 2;  // 8192*4
    constexpr size_t OFF_L  = OFF_CW + (size_t)T_DIM * 4;          // 8192*4
    constexpr size_t OFF_QW = OFF_L  + (size_t)T_DIM * 4;          // 1024*4
    constexpr size_t OFF_HT = OFF_QW + (size_t)J_DIM * 4;          // 256*4

    unsigned short* P  = (unsigned short*)(ws + OFF_P);
    unsigned short* Cm = (unsigned short*)(ws + OFF_CM);
    unsigned short* Qb = (unsigned short*)(ws + OFF_QB);
    unsigned short* QT = (unsigned short*)(ws + OFF_QT);
    float* cw = (float*)(ws + OFF_CW);
    float* l  = (float*)(ws + OFF_L);
    float* qw = (float*)(ws + OFF_QW);
    float* ht = (float*)(ws + OFF_HT);

    hipMemsetAsync(ht, 0, D_DIM * sizeof(float), stream);
    prep_ctx<<<dim3(T_DIM / 4), 256, 0, stream>>>(ctx, w, Cm, cw);
    prep_q<<<dim3(J_DIM / 4), 256, 0, stream>>>(qry, w, Qb, QT, qw);
    gemm_s<<<dim3(T_DIM / 128, J_DIM / 128), 256, 0, stream>>>(Cm, Qb, qw, P);
    rowstats<<<dim3(T_DIM / 16), 256, 0, stream>>>(P, cw, ctx, l, ht);
    gemm_o<<<dim3(T_DIM / 128, D_DIM / 64), 256, 0, stream>>>(P, QT, l, ht, ctx, G);
}

// Round 2
// 59.088 us; speedup vs baseline: 1.1079x; 1.1079x over previous
//
#include <hip/hip_runtime.h>
#include <stdint.h>

#define T_DIM 8192
#define J_DIM 1024
#define D_DIM 256

typedef __bf16 bf16x8 __attribute__((ext_vector_type(8)));
typedef float f32x4 __attribute__((ext_vector_type(4)));
typedef unsigned short u16x8 __attribute__((ext_vector_type(8)));
typedef unsigned short u16x4 __attribute__((ext_vector_type(4)));

__device__ inline unsigned short f2bf(float x) {
    unsigned u = __builtin_bit_cast(unsigned, x);
    u += 0x7FFFu + ((u >> 16) & 1u);
    return (unsigned short)(u >> 16);
}

// K0: fused prep. Blocks [0,2048): context path; [2048,2304): query path.
__global__ __launch_bounds__(256) void prep_all(const float* __restrict__ ctx,
                                                const float* __restrict__ qry,
                                                const float* __restrict__ w,
                                                unsigned short* __restrict__ Cm,
                                                float* __restrict__ cw,
                                                unsigned short* __restrict__ Qb,
                                                unsigned short* __restrict__ QT,
                                                float* __restrict__ qw) {
    int wid = threadIdx.x >> 6, lane = threadIdx.x & 63;
    if (blockIdx.x < 2048) {
        int t = blockIdx.x * 4 + wid;
        float4 c  = *(const float4*)(ctx + (size_t)t * D_DIM + lane * 4);
        float4 wm = *(const float4*)(w + 2 * D_DIM + lane * 4);
        float4 wc = *(const float4*)(w + lane * 4);
        u16x4 cmv;
        cmv[0] = f2bf(c.x * wm.x);
        cmv[1] = f2bf(c.y * wm.y);
        cmv[2] = f2bf(c.z * wm.z);
        cmv[3] = f2bf(c.w * wm.w);
        *(u16x4*)(Cm + (size_t)t * D_DIM + lane * 4) = cmv;
        float s = c.x * wc.x + c.y * wc.y + c.z * wc.z + c.w * wc.w;
        #pragma unroll
        for (int o = 1; o < 64; o <<= 1) s += __shfl_xor(s, o);
        if (lane == 0) cw[t] = s;
    } else {
        int j = (blockIdx.x - 2048) * 4 + wid;
        float4 c  = *(const float4*)(qry + (size_t)j * D_DIM + lane * 4);
        float4 wq = *(const float4*)(w + D_DIM + lane * 4);
        u16x4 qv;
        qv[0] = f2bf(c.x);
        qv[1] = f2bf(c.y);
        qv[2] = f2bf(c.z);
        qv[3] = f2bf(c.w);
        *(u16x4*)(Qb + (size_t)j * D_DIM + lane * 4) = qv;
        int d0 = lane * 4;
        QT[(size_t)(d0 + 0) * J_DIM + j] = qv[0];
        QT[(size_t)(d0 + 1) * J_DIM + j] = qv[1];
        QT[(size_t)(d0 + 2) * J_DIM + j] = qv[2];
        QT[(size_t)(d0 + 3) * J_DIM + j] = qv[3];
        float s = c.x * wq.x + c.y * wq.y + c.z * wq.z + c.w * wq.w;
        #pragma unroll
        for (int o = 1; o < 64; o <<= 1) s += __shfl_xor(s, o);
        if (lane == 0) qw[j] = s;
    }
}

// K1: P[t][j] = bf16(exp(Cm.Qb^T + qw)), plus fused row stats:
// lsum[t] += sum_j exp (f32, atomicAdd), rmax[t] = max_j exp (int atomicMax, positive floats).
// 128x128 tile, BK=64, 4 waves (2x2). 1D grid, bm-fast for XCD L2 reuse of Cm.
__global__ __launch_bounds__(256) void gemm_s(const unsigned short* __restrict__ Cm,
                                              const unsigned short* __restrict__ Qb,
                                              const float* __restrict__ qw,
                                              unsigned short* __restrict__ P,
                                              float* __restrict__ lsum,
                                              int* __restrict__ rmax) {
    __shared__ unsigned short SH[16384];          // As = SH[0:8192), Bs = SH[8192:16384)
    unsigned short* As = SH;
    unsigned short* Bs = SH + 8192;
    int tid = threadIdx.x;
    int lane = tid & 63, wv = tid >> 6;
    int wm = wv >> 1, wn = wv & 1;
    int bm = blockIdx.x & 63, bn = blockIdx.x >> 6;
    f32x4 acc[4][4] = {};

    for (int k0 = 0; k0 < 256; k0 += 64) {
        if (k0) __syncthreads();
        #pragma unroll
        for (int i = 0; i < 4; ++i) {
            int cid = tid + i * 256;           // chunk id, 8 bf16 per chunk
            int r = cid >> 3, cc = cid & 7;
            u16x8 av = *(const u16x8*)(Cm + (size_t)(bm * 128 + r) * 256 + k0 + cc * 8);
            *(u16x8*)(As + r * 64 + ((cc ^ (r & 7)) << 3)) = av;
            u16x8 bv = *(const u16x8*)(Qb + (size_t)(bn * 128 + r) * 256 + k0 + cc * 8);
            *(u16x8*)(Bs + r * 64 + ((cc ^ (r & 7)) << 3)) = bv;
        }
        __syncthreads();
        #pragma unroll
        for (int ks = 0; ks < 2; ++ks) {
            int klo = (lane >> 4) + ks * 4;    // chunk index along k
            bf16x8 af[4], bfr[4];
            #pragma unroll
            for (int f = 0; f < 4; ++f) {
                int ra = wm * 64 + f * 16 + (lane & 15);
                af[f] = __builtin_bit_cast(bf16x8,
                        *(const u16x8*)(As + ra * 64 + ((klo ^ (ra & 7)) << 3)));
                int rb = wn * 64 + f * 16 + (lane & 15);
                bfr[f] = __builtin_bit_cast(bf16x8,
                        *(const u16x8*)(Bs + rb * 64 + ((klo ^ (rb & 7)) << 3)));
            }
            #pragma unroll
            for (int m = 0; m < 4; ++m)
                #pragma unroll
                for (int n = 0; n < 4; ++n)
                    acc[m][n] = __builtin_amdgcn_mfma_f32_16x16x32_bf16(af[m], bfr[n], acc[m][n], 0, 0, 0);
        }
    }

    int rgrp = lane >> 4, cidx = lane & 15;

    // exp in place (f32)
    #pragma unroll
    for (int n = 0; n < 4; ++n) {
        int j = bn * 128 + wn * 64 + n * 16 + cidx;
        float qwv = qw[j];
        #pragma unroll
        for (int m = 0; m < 4; ++m)
            #pragma unroll
            for (int rg = 0; rg < 4; ++rg)
                acc[m][n][rg] = __expf(acc[m][n][rg] + qwv);
    }

    // fused row stats: per (m,rg) sum/max over this wave's 64-j span, then atomics
    #pragma unroll
    for (int m = 0; m < 4; ++m) {
        #pragma unroll
        for (int rg = 0; rg < 4; ++rg) {
            float s  = (acc[m][0][rg] + acc[m][1][rg]) + (acc[m][2][rg] + acc[m][3][rg]);
            float mx = fmaxf(fmaxf(acc[m][0][rg], acc[m][1][rg]),
                             fmaxf(acc[m][2][rg], acc[m][3][rg]));
            #pragma unroll
            for (int o = 1; o < 16; o <<= 1) {
                s += __shfl_xor(s, o);
                mx = fmaxf(mx, __shfl_xor(mx, o));
            }
            if (cidx == 0) {
                int trow = bm * 128 + wm * 64 + m * 16 + rgrp * 4 + rg;
                atomicAdd(lsum + trow, s);
                atomicMax(rmax + trow, __float_as_int(mx));
            }
        }
    }

    // stage bf16 P tile in LDS (swizzled), then coalesced u16x8 stores
    __syncthreads();                     // everyone done reading As/Bs
    #pragma unroll
    for (int m = 0; m < 4; ++m)
        #pragma unroll
        for (int n = 0; n < 4; ++n)
            #pragma unroll
            for (int rg = 0; rg < 4; ++rg) {
                int row = wm * 64 + m * 16 + rgrp * 4 + rg;
                int col = wn * 64 + n * 16 + cidx;
                int c8 = col >> 3;
                SH[row * 128 + ((c8 ^ (row & 7)) << 3) + (col & 7)] = f2bf(acc[m][n][rg]);
            }
    __syncthreads();
    const size_t pbase = (size_t)(bm * 128) * J_DIM + bn * 128;
    #pragma unroll
    for (int i = 0; i < 8; ++i) {
        int r = i * 16 + (tid >> 4);
        int c8 = tid & 15;
        u16x8 v = *(const u16x8*)(SH + r * 128 + ((c8 ^ (r & 7)) << 3));
        *(u16x8*)(P + pbase + (size_t)r * J_DIM + c8 * 8) = v;
    }
}

// K2: b[t] = log(rmax[t]) + cw[t]; htilde[d] += sum_t b[t]*ctx[t][d]
__global__ __launch_bounds__(256) void hb_kernel(const float* __restrict__ rmax,
                                                 const float* __restrict__ cw,
                                                 const float* __restrict__ ctx,
                                                 float* __restrict__ ht) {
    __shared__ float bsh[128];
    int tid = threadIdx.x;
    int t0 = blockIdx.x * 128;
    if (tid < 128) bsh[tid] = __logf(rmax[t0 + tid]) + cw[t0 + tid];
    __syncthreads();
    float pb = 0.f;
    #pragma unroll 8
    for (int r = 0; r < 128; ++r)
        pb += bsh[r] * ctx[(size_t)(t0 + r) * D_DIM + tid];
    atomicAdd(ht + tid, pb);
}

// K3: acc = P @ query (QT rows = B^T), epilogue writes all 4 G blocks.
// 128x64 tile, BK=64, 4 waves (2x2). 1D grid, bm-fast for XCD L2 reuse of P.
__global__ __launch_bounds__(256) void gemm_o(const unsigned short* __restrict__ P,
                                              const unsigned short* __restrict__ QT,
                                              const float* __restrict__ lsum,
                                              const float* __restrict__ htilde,
                                              const float* __restrict__ ctx,
                                              float* __restrict__ G) {
    __shared__ unsigned short As[128 * 64];
    __shared__ unsigned short Bs[64 * 64];
    int tid = threadIdx.x;
    int lane = tid & 63, wv = tid >> 6;
    int wm = wv >> 1, wn = wv & 1;
    int bm = blockIdx.x & 63, bn = blockIdx.x >> 6;
    f32x4 acc[4][2] = {};

    for (int k0 = 0; k0 < 1024; k0 += 64) {
        if (k0) __syncthreads();
        #pragma unroll
        for (int i = 0; i < 4; ++i) {
            int cid = tid + i * 256;
            int r = cid >> 3, cc = cid & 7;
            u16x8 av = *(const u16x8*)(P + (size_t)(bm * 128 + r) * J_DIM + k0 + cc * 8);
            *(u16x8*)(As + r * 64 + ((cc ^ (r & 7)) << 3)) = av;
        }
        #pragma unroll
        for (int i = 0; i < 2; ++i) {
            int cid = tid + i * 256;
            int r = cid >> 3, cc = cid & 7;    // r in 0..63
            u16x8 bv = *(const u16x8*)(QT + (size_t)(bn * 64 + r) * J_DIM + k0 + cc * 8);
            *(u16x8*)(Bs + r * 64 + ((cc ^ (r & 7)) << 3)) = bv;
        }
        __syncthreads();
        #pragma unroll
        for (int ks = 0; ks < 2; ++ks) {
            int klo = (lane >> 4) + ks * 4;
            bf16x8 af[4], bfr[2];
            #pragma unroll
            for (int f = 0; f < 4; ++f) {
                int ra = wm * 64 + f * 16 + (lane & 15);
                af[f] = __builtin_bit_cast(bf16x8,
                        *(const u16x8*)(As + ra * 64 + ((klo ^ (ra & 7)) << 3)));
            }
            #pragma unroll
            for (int f = 0; f < 2; ++f) {
                int rb = wn * 32 + f * 16 + (lane & 15);
                bfr[f] = __builtin_bit_cast(bf16x8,
                        *(const u16x8*)(Bs + rb * 64 + ((klo ^ (rb & 7)) << 3)));
            }
            #pragma unroll
            for (int m = 0; m < 4; ++m)
                #pragma unroll
                for (int n = 0; n < 2; ++n)
                    acc[m][n] = __builtin_amdgcn_mfma_f32_16x16x32_bf16(af[m], bfr[n], acc[m][n], 0, 0, 0);
        }
    }

    int rgrp = lane >> 4, cidx = lane & 15;
    #pragma unroll
    for (int m = 0; m < 4; ++m) {
        #pragma unroll
        for (int rg = 0; rg < 4; ++rg) {
            int t = bm * 128 + wm * 64 + m * 16 + rgrp * 4 + rg;
            float linv = 1.0f / lsum[t];
            float* gr = G + (size_t)t * 1024;
            #pragma unroll
            for (int n = 0; n < 2; ++n) {
                int d = bn * 64 + wn * 32 + n * 16 + cidx;
                float val = acc[m][n][rg] * linv;
                float c = ctx[(size_t)t * D_DIM + d];
                gr[d]       = c;
                gr[256 + d] = val;
                gr[512 + d] = c * val;
                gr[768 + d] = c * htilde[d];
            }
        }
    }
}

extern "C" void kernel_launch(void* const* d_in, const int* in_sizes, int n_in,
                              void* d_out, int out_size, void* d_ws, size_t ws_size,
                              hipStream_t stream) {
    (void)in_sizes; (void)n_in; (void)out_size; (void)ws_size;
    const float* ctx = (const float*)d_in[0];
    const float* qry = (const float*)d_in[1];
    const float* w   = (const float*)d_in[2];
    float* G = (float*)d_out;
    char* ws = (char*)d_ws;

    constexpr size_t OFF_P  = 0;                                   // 16 MiB
    constexpr size_t OFF_CM = OFF_P  + (size_t)T_DIM * J_DIM * 2;  // 4 MiB
    constexpr size_t OFF_QB = OFF_CM + (size_t)T_DIM * D_DIM * 2;
    constexpr size_t OFF_QT = OFF_QB + (size_t)J_DIM * D_DIM * 2;
    constexpr size_t OFF_CW = OFF_QT + (size_t)D_DIM * J_DIM * 2;
    constexpr size_t OFF_QW = OFF_CW + (size_t)T_DIM * 4;
    constexpr size_t OFF_ST = OFF_QW + (size_t)J_DIM * 4;          // stats: lsum|rmax|ht

    unsigned short* P  = (unsigned short*)(ws + OFF_P);
    unsigned short* Cm = (unsigned short*)(ws + OFF_CM);
    unsigned short* Qb = (unsigned short*)(ws + OFF_QB);
    unsigned short* QT = (unsigned short*)(ws + OFF_QT);
    float* cw    = (float*)(ws + OFF_CW);
    float* qw    = (float*)(ws + OFF_QW);
    float* stats = (float*)(ws + OFF_ST);
    float* lsum  = stats;                 // 8192
    float* rmax  = stats + T_DIM;         // 8192 (float bits via int atomicMax)
    float* ht    = stats + 2 * T_DIM;     // 256

    hipMemsetAsync(stats, 0, (2 * T_DIM + D_DIM) * sizeof(float), stream);
    prep_all<<<dim3(2048 + 256), 256, 0, stream>>>(ctx, qry, w, Cm, cw, Qb, QT, qw);
    gemm_s<<<dim3(512), 256, 0, stream>>>(Cm, Qb, qw, P, lsum, (int*)rmax);
    hb_kernel<<<dim3(64), 256, 0, stream>>>(rmax, cw, ctx, ht);
    gemm_o<<<dim3(256), 256, 0, stream>>>(P, QT, lsum, ht, ctx, G);
}

// Round 3
// 58.497 us; speedup vs baseline: 1.1191x; 1.0101x over previous
//
#include <hip/hip_runtime.h>
#include <stdint.h>

#define T_DIM 8192
#define J_DIM 1024
#define D_DIM 256

typedef __bf16 bf16x8 __attribute__((ext_vector_type(8)));
typedef float f32x4 __attribute__((ext_vector_type(4)));
typedef unsigned short u16x8 __attribute__((ext_vector_type(8)));
typedef unsigned short u16x4 __attribute__((ext_vector_type(4)));

__device__ inline unsigned short f2bf(float x) {
    unsigned u = __builtin_bit_cast(unsigned, x);
    u += 0x7FFFu + ((u >> 16) & 1u);
    return (unsigned short)(u >> 16);
}

// K-1: zero the stats region (lsum | rmax | ht). rocclr fillBuffer was 44 us for
// this 66 KB buffer; a plain store kernel is ~1 us.
__global__ __launch_bounds__(256) void zero_stats(float* __restrict__ stats) {
    stats[blockIdx.x * 256 + threadIdx.x] = 0.0f;
}

// K0: fused prep. Blocks [0,2048): context path; [2048,2304): query path.
__global__ __launch_bounds__(256) void prep_all(const float* __restrict__ ctx,
                                                const float* __restrict__ qry,
                                                const float* __restrict__ w,
                                                unsigned short* __restrict__ Cm,
                                                float* __restrict__ cw,
                                                unsigned short* __restrict__ Qb,
                                                unsigned short* __restrict__ QT,
                                                float* __restrict__ qw) {
    int wid = threadIdx.x >> 6, lane = threadIdx.x & 63;
    if (blockIdx.x < 2048) {
        int t = blockIdx.x * 4 + wid;
        float4 c  = *(const float4*)(ctx + (size_t)t * D_DIM + lane * 4);
        float4 wm = *(const float4*)(w + 2 * D_DIM + lane * 4);
        float4 wc = *(const float4*)(w + lane * 4);
        u16x4 cmv;
        cmv[0] = f2bf(c.x * wm.x);
        cmv[1] = f2bf(c.y * wm.y);
        cmv[2] = f2bf(c.z * wm.z);
        cmv[3] = f2bf(c.w * wm.w);
        *(u16x4*)(Cm + (size_t)t * D_DIM + lane * 4) = cmv;
        float s = c.x * wc.x + c.y * wc.y + c.z * wc.z + c.w * wc.w;
        #pragma unroll
        for (int o = 1; o < 64; o <<= 1) s += __shfl_xor(s, o);
        if (lane == 0) cw[t] = s;
    } else {
        int j = (blockIdx.x - 2048) * 4 + wid;
        float4 c  = *(const float4*)(qry + (size_t)j * D_DIM + lane * 4);
        float4 wq = *(const float4*)(w + D_DIM + lane * 4);
        u16x4 qv;
        qv[0] = f2bf(c.x);
        qv[1] = f2bf(c.y);
        qv[2] = f2bf(c.z);
        qv[3] = f2bf(c.w);
        *(u16x4*)(Qb + (size_t)j * D_DIM + lane * 4) = qv;
        int d0 = lane * 4;
        QT[(size_t)(d0 + 0) * J_DIM + j] = qv[0];
        QT[(size_t)(d0 + 1) * J_DIM + j] = qv[1];
        QT[(size_t)(d0 + 2) * J_DIM + j] = qv[2];
        QT[(size_t)(d0 + 3) * J_DIM + j] = qv[3];
        float s = c.x * wq.x + c.y * wq.y + c.z * wq.z + c.w * wq.w;
        #pragma unroll
        for (int o = 1; o < 64; o <<= 1) s += __shfl_xor(s, o);
        if (lane == 0) qw[j] = s;
    }
}

// K1: P[t][j] = bf16(exp(Cm.Qb^T + qw)), plus fused row stats:
// lsum[t] += sum_j exp (f32, atomicAdd), rmax[t] = max_j exp (int atomicMax, positive floats).
// 128x128 tile, BK=64, 4 waves (2x2). 1D grid, bm-fast for XCD L2 reuse of Cm.
__global__ __launch_bounds__(256) void gemm_s(const unsigned short* __restrict__ Cm,
                                              const unsigned short* __restrict__ Qb,
                                              const float* __restrict__ qw,
                                              unsigned short* __restrict__ P,
                                              float* __restrict__ lsum,
                                              int* __restrict__ rmax) {
    __shared__ unsigned short SH[16384];          // As = SH[0:8192), Bs = SH[8192:16384)
    unsigned short* As = SH;
    unsigned short* Bs = SH + 8192;
    int tid = threadIdx.x;
    int lane = tid & 63, wv = tid >> 6;
    int wm = wv >> 1, wn = wv & 1;
    int bm = blockIdx.x & 63, bn = blockIdx.x >> 6;
    f32x4 acc[4][4] = {};

    for (int k0 = 0; k0 < 256; k0 += 64) {
        if (k0) __syncthreads();
        #pragma unroll
        for (int i = 0; i < 4; ++i) {
            int cid = tid + i * 256;           // chunk id, 8 bf16 per chunk
            int r = cid >> 3, cc = cid & 7;
            u16x8 av = *(const u16x8*)(Cm + (size_t)(bm * 128 + r) * 256 + k0 + cc * 8);
            *(u16x8*)(As + r * 64 + ((cc ^ (r & 7)) << 3)) = av;
            u16x8 bv = *(const u16x8*)(Qb + (size_t)(bn * 128 + r) * 256 + k0 + cc * 8);
            *(u16x8*)(Bs + r * 64 + ((cc ^ (r & 7)) << 3)) = bv;
        }
        __syncthreads();
        #pragma unroll
        for (int ks = 0; ks < 2; ++ks) {
            int klo = (lane >> 4) + ks * 4;    // chunk index along k
            bf16x8 af[4], bfr[4];
            #pragma unroll
            for (int f = 0; f < 4; ++f) {
                int ra = wm * 64 + f * 16 + (lane & 15);
                af[f] = __builtin_bit_cast(bf16x8,
                        *(const u16x8*)(As + ra * 64 + ((klo ^ (ra & 7)) << 3)));
                int rb = wn * 64 + f * 16 + (lane & 15);
                bfr[f] = __builtin_bit_cast(bf16x8,
                        *(const u16x8*)(Bs + rb * 64 + ((klo ^ (rb & 7)) << 3)));
            }
            #pragma unroll
            for (int m = 0; m < 4; ++m)
                #pragma unroll
                for (int n = 0; n < 4; ++n)
                    acc[m][n] = __builtin_amdgcn_mfma_f32_16x16x32_bf16(af[m], bfr[n], acc[m][n], 0, 0, 0);
        }
    }

    int rgrp = lane >> 4, cidx = lane & 15;

    // exp in place (f32)
    #pragma unroll
    for (int n = 0; n < 4; ++n) {
        int j = bn * 128 + wn * 64 + n * 16 + cidx;
        float qwv = qw[j];
        #pragma unroll
        for (int m = 0; m < 4; ++m)
            #pragma unroll
            for (int rg = 0; rg < 4; ++rg)
                acc[m][n][rg] = __expf(acc[m][n][rg] + qwv);
    }

    // fused row stats: per (m,rg) sum/max over this wave's 64-j span, then atomics
    #pragma unroll
    for (int m = 0; m < 4; ++m) {
        #pragma unroll
        for (int rg = 0; rg < 4; ++rg) {
            float s  = (acc[m][0][rg] + acc[m][1][rg]) + (acc[m][2][rg] + acc[m][3][rg]);
            float mx = fmaxf(fmaxf(acc[m][0][rg], acc[m][1][rg]),
                             fmaxf(acc[m][2][rg], acc[m][3][rg]));
            #pragma unroll
            for (int o = 1; o < 16; o <<= 1) {
                s += __shfl_xor(s, o);
                mx = fmaxf(mx, __shfl_xor(mx, o));
            }
            if (cidx == 0) {
                int trow = bm * 128 + wm * 64 + m * 16 + rgrp * 4 + rg;
                atomicAdd(lsum + trow, s);
                atomicMax(rmax + trow, __float_as_int(mx));
            }
        }
    }

    // stage bf16 P tile in LDS (swizzled), then coalesced u16x8 stores
    __syncthreads();                     // everyone done reading As/Bs
    #pragma unroll
    for (int m = 0; m < 4; ++m)
        #pragma unroll
        for (int n = 0; n < 4; ++n)
            #pragma unroll
            for (int rg = 0; rg < 4; ++rg) {
                int row = wm * 64 + m * 16 + rgrp * 4 + rg;
                int col = wn * 64 + n * 16 + cidx;
                int c8 = col >> 3;
                SH[row * 128 + ((c8 ^ (row & 7)) << 3) + (col & 7)] = f2bf(acc[m][n][rg]);
            }
    __syncthreads();
    const size_t pbase = (size_t)(bm * 128) * J_DIM + bn * 128;
    #pragma unroll
    for (int i = 0; i < 8; ++i) {
        int r = i * 16 + (tid >> 4);
        int c8 = tid & 15;
        u16x8 v = *(const u16x8*)(SH + r * 128 + ((c8 ^ (r & 7)) << 3));
        *(u16x8*)(P + pbase + (size_t)r * J_DIM + c8 * 8) = v;
    }
}

// K2: b[t] = log(rmax[t]) + cw[t]; htilde[d] += sum_t b[t]*ctx[t][d]
__global__ __launch_bounds__(256) void hb_kernel(const float* __restrict__ rmax,
                                                 const float* __restrict__ cw,
                                                 const float* __restrict__ ctx,
                                                 float* __restrict__ ht) {
    __shared__ float bsh[128];
    int tid = threadIdx.x;
    int t0 = blockIdx.x * 128;
    if (tid < 128) bsh[tid] = __logf(rmax[t0 + tid]) + cw[t0 + tid];
    __syncthreads();
    float pb = 0.f;
    #pragma unroll 8
    for (int r = 0; r < 128; ++r)
        pb += bsh[r] * ctx[(size_t)(t0 + r) * D_DIM + tid];
    atomicAdd(ht + tid, pb);
}

// K3: acc = P @ query (QT rows = B^T), epilogue writes all 4 G blocks.
// 128x64 tile, BK=64, 4 waves (2x2). 1D grid, bm-fast for XCD L2 reuse of P.
__global__ __launch_bounds__(256) void gemm_o(const unsigned short* __restrict__ P,
                                              const unsigned short* __restrict__ QT,
                                              const float* __restrict__ lsum,
                                              const float* __restrict__ htilde,
                                              const float* __restrict__ ctx,
                                              float* __restrict__ G) {
    __shared__ unsigned short As[128 * 64];
    __shared__ unsigned short Bs[64 * 64];
    int tid = threadIdx.x;
    int lane = tid & 63, wv = tid >> 6;
    int wm = wv >> 1, wn = wv & 1;
    int bm = blockIdx.x & 63, bn = blockIdx.x >> 6;
    f32x4 acc[4][2] = {};

    for (int k0 = 0; k0 < 1024; k0 += 64) {
        if (k0) __syncthreads();
        #pragma unroll
        for (int i = 0; i < 4; ++i) {
            int cid = tid + i * 256;
            int r = cid >> 3, cc = cid & 7;
            u16x8 av = *(const u16x8*)(P + (size_t)(bm * 128 + r) * J_DIM + k0 + cc * 8);
            *(u16x8*)(As + r * 64 + ((cc ^ (r & 7)) << 3)) = av;
        }
        #pragma unroll
        for (int i = 0; i < 2; ++i) {
            int cid = tid + i * 256;
            int r = cid >> 3, cc = cid & 7;    // r in 0..63
            u16x8 bv = *(const u16x8*)(QT + (size_t)(bn * 64 + r) * J_DIM + k0 + cc * 8);
            *(u16x8*)(Bs + r * 64 + ((cc ^ (r & 7)) << 3)) = bv;
        }
        __syncthreads();
        #pragma unroll
        for (int ks = 0; ks < 2; ++ks) {
            int klo = (lane >> 4) + ks * 4;
            bf16x8 af[4], bfr[2];
            #pragma unroll
            for (int f = 0; f < 4; ++f) {
                int ra = wm * 64 + f * 16 + (lane & 15);
                af[f] = __builtin_bit_cast(bf16x8,
                        *(const u16x8*)(As + ra * 64 + ((klo ^ (ra & 7)) << 3)));
            }
            #pragma unroll
            for (int f = 0; f < 2; ++f) {
                int rb = wn * 32 + f * 16 + (lane & 15);
                bfr[f] = __builtin_bit_cast(bf16x8,
                        *(const u16x8*)(Bs + rb * 64 + ((klo ^ (rb & 7)) << 3)));
            }
            #pragma unroll
            for (int m = 0; m < 4; ++m)
                #pragma unroll
                for (int n = 0; n < 2; ++n)
                    acc[m][n] = __builtin_amdgcn_mfma_f32_16x16x32_bf16(af[m], bfr[n], acc[m][n], 0, 0, 0);
        }
    }

    int rgrp = lane >> 4, cidx = lane & 15;
    #pragma unroll
    for (int m = 0; m < 4; ++m) {
        #pragma unroll
        for (int rg = 0; rg < 4; ++rg) {
            int t = bm * 128 + wm * 64 + m * 16 + rgrp * 4 + rg;
            float linv = 1.0f / lsum[t];
            float* gr = G + (size_t)t * 1024;
            #pragma unroll
            for (int n = 0; n < 2; ++n) {
                int d = bn * 64 + wn * 32 + n * 16 + cidx;
                float val = acc[m][n][rg] * linv;
                float c = ctx[(size_t)t * D_DIM + d];
                gr[d]       = c;
                gr[256 + d] = val;
                gr[512 + d] = c * val;
                gr[768 + d] = c * htilde[d];
            }
        }
    }
}

extern "C" void kernel_launch(void* const* d_in, const int* in_sizes, int n_in,
                              void* d_out, int out_size, void* d_ws, size_t ws_size,
                              hipStream_t stream) {
    (void)in_sizes; (void)n_in; (void)out_size; (void)ws_size;
    const float* ctx = (const float*)d_in[0];
    const float* qry = (const float*)d_in[1];
    const float* w   = (const float*)d_in[2];
    float* G = (float*)d_out;
    char* ws = (char*)d_ws;

    constexpr size_t OFF_P  = 0;                                   // 16 MiB
    constexpr size_t OFF_CM = OFF_P  + (size_t)T_DIM * J_DIM * 2;  // 4 MiB
    constexpr size_t OFF_QB = OFF_CM + (size_t)T_DIM * D_DIM * 2;
    constexpr size_t OFF_QT = OFF_QB + (size_t)J_DIM * D_DIM * 2;
    constexpr size_t OFF_CW = OFF_QT + (size_t)D_DIM * J_DIM * 2;
    constexpr size_t OFF_QW = OFF_CW + (size_t)T_DIM * 4;
    constexpr size_t OFF_ST = OFF_QW + (size_t)J_DIM * 4;          // stats: lsum|rmax|ht

    unsigned short* P  = (unsigned short*)(ws + OFF_P);
    unsigned short* Cm = (unsigned short*)(ws + OFF_CM);
    unsigned short* Qb = (unsigned short*)(ws + OFF_QB);
    unsigned short* QT = (unsigned short*)(ws + OFF_QT);
    float* cw    = (float*)(ws + OFF_CW);
    float* qw    = (float*)(ws + OFF_QW);
    float* stats = (float*)(ws + OFF_ST);
    float* lsum  = stats;                 // 8192
    float* rmax  = stats + T_DIM;         // 8192 (float bits via int atomicMax)
    float* ht    = stats + 2 * T_DIM;     // 256

    zero_stats<<<dim3((2 * T_DIM + D_DIM) / 256 + 1), 256, 0, stream>>>(stats);
    prep_all<<<dim3(2048 + 256), 256, 0, stream>>>(ctx, qry, w, Cm, cw, Qb, QT, qw);
    gemm_s<<<dim3(512), 256, 0, stream>>>(Cm, Qb, qw, P, lsum, (int*)rmax);
    hb_kernel<<<dim3(64), 256, 0, stream>>>(rmax, cw, ctx, ht);
    gemm_o<<<dim3(256), 256, 0, stream>>>(P, QT, lsum, ht, ctx, G);
}

// Round 4
// 57.444 us; speedup vs baseline: 1.1396x; 1.0183x over previous
//
#include <hip/hip_runtime.h>
#include <stdint.h>

#define T_DIM 8192
#define J_DIM 1024
#define D_DIM 256
#define BM 32
#define JT 64

typedef __bf16 bf16x8 __attribute__((ext_vector_type(8)));
typedef float f32x4 __attribute__((ext_vector_type(4)));
typedef unsigned short u16x8 __attribute__((ext_vector_type(8)));
typedef unsigned short u16x4 __attribute__((ext_vector_type(4)));

__device__ inline unsigned short f2bf(float x) {
    unsigned u = __builtin_bit_cast(unsigned, x);
    u += 0x7FFFu + ((u >> 16) & 1u);
    return (unsigned short)(u >> 16);
}

// K0: query prep (Qb row-major bf16, QT transposed bf16, qw) + zero ht (block 256).
__global__ __launch_bounds__(256) void prep_q(const float* __restrict__ qry,
                                              const float* __restrict__ w,
                                              unsigned short* __restrict__ Qb,
                                              unsigned short* __restrict__ QT,
                                              float* __restrict__ qw,
                                              float* __restrict__ ht) {
    if (blockIdx.x == 256) {
        ht[threadIdx.x] = 0.0f;
        return;
    }
    int wid = threadIdx.x >> 6, lane = threadIdx.x & 63;
    int j = blockIdx.x * 4 + wid;
    float4 c  = *(const float4*)(qry + (size_t)j * D_DIM + lane * 4);
    float4 wq = *(const float4*)(w + D_DIM + lane * 4);
    u16x4 qv;
    qv[0] = f2bf(c.x);
    qv[1] = f2bf(c.y);
    qv[2] = f2bf(c.z);
    qv[3] = f2bf(c.w);
    *(u16x4*)(Qb + (size_t)j * D_DIM + lane * 4) = qv;
    int d0 = lane * 4;
    QT[(size_t)(d0 + 0) * J_DIM + j] = qv[0];
    QT[(size_t)(d0 + 1) * J_DIM + j] = qv[1];
    QT[(size_t)(d0 + 2) * J_DIM + j] = qv[2];
    QT[(size_t)(d0 + 3) * J_DIM + j] = qv[3];
    float s = c.x * wq.x + c.y * wq.y + c.z * wq.z + c.w * wq.w;
    #pragma unroll
    for (int o = 1; o < 64; o <<= 1) s += __shfl_xor(s, o);
    if (lane == 0) qw[j] = s;
}

// K1: fused flash-style main. 256 blocks x 512 threads (8 waves), 1 block/CU.
// Block owns 32 t-rows. Loop over 16 j-tiles of 64:
//   S = Cm @ Qb^T (1 frag/wave), exp (+row stats in regs), P-tile to LDS,
//   O += P @ Q (2x2 frags/wave over its 32-d slice).
// Epilogue: exact lsum/rmax per row (no atomics), b -> global, G cols 0..2.
extern "C" __global__ __launch_bounds__(512) void fused_main(
        const float* __restrict__ ctx, const float* __restrict__ w,
        const unsigned short* __restrict__ Qb, const unsigned short* __restrict__ QT,
        const float* __restrict__ qw, float* __restrict__ bglob,
        float* __restrict__ G) {
    extern __shared__ char smem[];
    float* ctxS          = (float*)smem;                          // [32][256] f32   32768
    unsigned short* CmS  = (unsigned short*)(smem + 32768);       // [32][256] bf16  16384
    unsigned short* QbS  = (unsigned short*)(smem + 49152);       // [64][256] bf16  32768
    unsigned short* QtS  = (unsigned short*)(smem + 81920);       // [256][64] bf16  32768
    unsigned short* PS   = (unsigned short*)(smem + 114688);      // [32][64]  bf16   4096
    float* statSum       = (float*)(smem + 118784);               // [4][32]          512
    float* statMax       = (float*)(smem + 119296);               // [4][32]          512
    float* cwS           = (float*)(smem + 119808);               // [32]             128
    float* linvS         = (float*)(smem + 119936);               // [32]             128

    int tid = threadIdx.x, lane = tid & 63, wv = tid >> 6;
    int cidx = lane & 15, rgrp = lane >> 4;
    int mw = wv >> 2, nw = wv & 3;          // S-frag (rows mw*16.., cols nw*16..)
    int t0 = blockIdx.x * BM;
    int srow = tid >> 4, c16 = tid & 15;    // staging/epilogue mapping

    // ---- stage ctx -> ctxS (f32) + CmS (bf16, swizzled) + cw row dots
    {
        float pc = 0.f;
        #pragma unroll
        for (int q = 0; q < 4; ++q) {
            int d = q * 64 + c16 * 4;
            float4 c  = *(const float4*)(ctx + (size_t)(t0 + srow) * D_DIM + d);
            float4 wm = *(const float4*)(w + 2 * D_DIM + d);
            float4 wc = *(const float4*)(w + d);
            *(float4*)(ctxS + srow * 256 + d) = c;
            u16x4 cm;
            cm[0] = f2bf(c.x * wm.x);
            cm[1] = f2bf(c.y * wm.y);
            cm[2] = f2bf(c.z * wm.z);
            cm[3] = f2bf(c.w * wm.w);
            int kc = d >> 3;
            *(u16x4*)(CmS + srow * 256 + ((kc ^ (srow & 7)) << 3) + (d & 7)) = cm;
            pc += c.x * wc.x + c.y * wc.y + c.z * wc.z + c.w * wc.w;
        }
        #pragma unroll
        for (int o = 1; o < 16; o <<= 1) pc += __shfl_xor(pc, o);
        if (c16 == 0) cwS[srow] = pc;
    }

    f32x4 oacc[2][2] = {};
    float psum[4] = {0.f, 0.f, 0.f, 0.f};
    float pmax[4] = {0.f, 0.f, 0.f, 0.f};

    for (int jt = 0; jt < J_DIM / JT; ++jt) {
        int j0 = jt * JT;
        __syncthreads();          // previous iter's PV reads of QtS/PS done
        // stage QbS [64][256] and QtS [256][64] (both chunk-XOR swizzled)
        #pragma unroll
        for (int i = 0; i < 4; ++i) {
            int cid = tid + i * 512;
            int r = cid >> 5, kc = cid & 31;
            u16x8 v = *(const u16x8*)(Qb + (size_t)(j0 + r) * D_DIM + kc * 8);
            *(u16x8*)(QbS + r * 256 + ((kc ^ (r & 7)) << 3)) = v;
        }
        #pragma unroll
        for (int i = 0; i < 4; ++i) {
            int cid = tid + i * 512;
            int r = cid >> 3, kc = cid & 7;
            u16x8 v = *(const u16x8*)(QT + (size_t)r * J_DIM + j0 + kc * 8);
            *(u16x8*)(QtS + r * 64 + ((kc ^ (r & 7)) << 3)) = v;
        }
        __syncthreads();

        // S-MFMA: one 16x16x(K=256) frag per wave
        f32x4 sacc = {0.f, 0.f, 0.f, 0.f};
        int arow = mw * 16 + cidx;
        int brow = nw * 16 + cidx;
        #pragma unroll
        for (int step = 0; step < 8; ++step) {
            int klo = step * 4 + rgrp;
            bf16x8 a = __builtin_bit_cast(bf16x8,
                    *(const u16x8*)(CmS + arow * 256 + ((klo ^ (arow & 7)) << 3)));
            bf16x8 b = __builtin_bit_cast(bf16x8,
                    *(const u16x8*)(QbS + brow * 256 + ((klo ^ (brow & 7)) << 3)));
            sacc = __builtin_amdgcn_mfma_f32_16x16x32_bf16(a, b, sacc, 0, 0, 0);
        }

        // exp + register row-stats + P-tile write
        float qwv = qw[j0 + nw * 16 + cidx];
        int pcol = nw * 16 + cidx;
        int pbase = mw * 16 + rgrp * 4;
        #pragma unroll
        for (int reg = 0; reg < 4; ++reg) {
            float p = __expf(sacc[reg] + qwv);
            psum[reg] += p;
            pmax[reg] = fmaxf(pmax[reg], p);
            int prow = pbase + reg;
            PS[prow * 64 + (((pcol >> 3) ^ (prow & 7)) << 3) + (pcol & 7)] = f2bf(p);
        }
        __syncthreads();

        // PV: O(32 x 32d-slice) += P(32x64) @ Q(64 x d)
        #pragma unroll
        for (int ks = 0; ks < 2; ++ks) {
            int klo = ks * 4 + rgrp;
            bf16x8 pa[2], qb2[2];
            #pragma unroll
            for (int m = 0; m < 2; ++m) {
                int prow = m * 16 + cidx;
                pa[m] = __builtin_bit_cast(bf16x8,
                        *(const u16x8*)(PS + prow * 64 + ((klo ^ (prow & 7)) << 3)));
            }
            #pragma unroll
            for (int n = 0; n < 2; ++n) {
                int drow = wv * 32 + n * 16 + cidx;
                qb2[n] = __builtin_bit_cast(bf16x8,
                        *(const u16x8*)(QtS + drow * 64 + ((klo ^ (drow & 7)) << 3)));
            }
            #pragma unroll
            for (int m = 0; m < 2; ++m)
                #pragma unroll
                for (int n = 0; n < 2; ++n)
                    oacc[m][n] = __builtin_amdgcn_mfma_f32_16x16x32_bf16(pa[m], qb2[n], oacc[m][n], 0, 0, 0);
        }
    }

    // ---- exact row stats: reduce over cidx, combine 4 nw-slices via LDS
    #pragma unroll
    for (int reg = 0; reg < 4; ++reg) {
        #pragma unroll
        for (int o = 1; o < 16; o <<= 1) {
            psum[reg] += __shfl_xor(psum[reg], o);
            pmax[reg] = fmaxf(pmax[reg], __shfl_xor(pmax[reg], o));
        }
    }
    __syncthreads();
    if (cidx == 0) {
        #pragma unroll
        for (int reg = 0; reg < 4; ++reg) {
            int row = mw * 16 + rgrp * 4 + reg;
            statSum[nw * 32 + row] = psum[reg];
            statMax[nw * 32 + row] = pmax[reg];
        }
    }
    __syncthreads();
    if (tid < 32) {
        float s = (statSum[tid] + statSum[32 + tid]) + (statSum[64 + tid] + statSum[96 + tid]);
        float mx = fmaxf(fmaxf(statMax[tid], statMax[32 + tid]),
                         fmaxf(statMax[64 + tid], statMax[96 + tid]));
        linvS[tid] = 1.0f / s;
        bglob[t0 + tid] = __logf(mx) + cwS[tid];
    }
    __syncthreads();

    // ---- G col 0: context copy (coalesced f32x4)
    #pragma unroll
    for (int q = 0; q < 4; ++q) {
        int d = q * 64 + c16 * 4;
        *(float4*)(G + (size_t)(t0 + srow) * 1024 + d) = *(const float4*)(ctxS + srow * 256 + d);
    }
    // ---- G cols 1,2 from O accumulators
    #pragma unroll
    for (int m = 0; m < 2; ++m) {
        #pragma unroll
        for (int reg = 0; reg < 4; ++reg) {
            int row = m * 16 + rgrp * 4 + reg;
            float linv = linvS[row];
            float* gr = G + (size_t)(t0 + row) * 1024;
            #pragma unroll
            for (int n = 0; n < 2; ++n) {
                int col = wv * 32 + n * 16 + cidx;
                float val = oacc[m][n][reg] * linv;
                float c = ctxS[row * 256 + col];
                gr[256 + col] = val;
                gr[512 + col] = val * c;
            }
        }
    }
}

// K2: htilde[d] += sum over 128 rows of b[t]*ctx[t][d]
__global__ __launch_bounds__(256) void ht_accum(const float* __restrict__ b,
                                                const float* __restrict__ ctx,
                                                float* __restrict__ ht) {
    __shared__ float bsh[128];
    int tid = threadIdx.x;
    int t0b = blockIdx.x * 128;
    if (tid < 128) bsh[tid] = b[t0b + tid];
    __syncthreads();
    float pb = 0.f;
    #pragma unroll 8
    for (int r = 0; r < 128; ++r)
        pb += bsh[r] * ctx[(size_t)(t0b + r) * D_DIM + tid];
    atomicAdd(ht + tid, pb);
}

// K3: G col 3 = ctx * htilde (fully coalesced float4)
__global__ __launch_bounds__(256) void g3_write(const float* __restrict__ ctx,
                                                const float* __restrict__ ht,
                                                float* __restrict__ G) {
    int gt = blockIdx.x * 256 + threadIdx.x;
    int idx = gt * 4;
    int t = idx >> 8, d = idx & 255;
    float4 c = *(const float4*)(ctx + (size_t)t * D_DIM + d);
    float4 h = *(const float4*)(ht + d);
    float4 o;
    o.x = c.x * h.x; o.y = c.y * h.y; o.z = c.z * h.z; o.w = c.w * h.w;
    *(float4*)(G + (size_t)t * 1024 + 768 + d) = o;
}

extern "C" void kernel_launch(void* const* d_in, const int* in_sizes, int n_in,
                              void* d_out, int out_size, void* d_ws, size_t ws_size,
                              hipStream_t stream) {
    (void)in_sizes; (void)n_in; (void)out_size; (void)ws_size;
    const float* ctx = (const float*)d_in[0];
    const float* qry = (const float*)d_in[1];
    const float* w   = (const float*)d_in[2];
    float* G = (float*)d_out;
    char* ws = (char*)d_ws;

    constexpr size_t OFF_QB = 0;                                    // 512 KiB
    constexpr size_t OFF_QT = OFF_QB + (size_t)J_DIM * D_DIM * 2;   // 512 KiB
    constexpr size_t OFF_QW = OFF_QT + (size_t)D_DIM * J_DIM * 2;   // 4 KiB
    constexpr size_t OFF_B  = OFF_QW + (size_t)J_DIM * 4;           // 32 KiB
    constexpr size_t OFF_HT = OFF_B  + (size_t)T_DIM * 4;           // 1 KiB

    unsigned short* Qb = (unsigned short*)(ws + OFF_QB);
    unsigned short* QT = (unsigned short*)(ws + OFF_QT);
    float* qw = (float*)(ws + OFF_QW);
    float* b  = (float*)(ws + OFF_B);
    float* ht = (float*)(ws + OFF_HT);

    constexpr int SMEM_BYTES = 120064;
    hipFuncSetAttribute((const void*)fused_main,
                        hipFuncAttributeMaxDynamicSharedMemorySize, SMEM_BYTES);

    prep_q<<<dim3(257), 256, 0, stream>>>(qry, w, Qb, QT, qw, ht);
    fused_main<<<dim3(T_DIM / BM), 512, SMEM_BYTES, stream>>>(ctx, w, Qb, QT, qw, b, G);
    ht_accum<<<dim3(T_DIM / 128), 256, 0, stream>>>(b, ctx, ht);
    g3_write<<<dim3(T_DIM * D_DIM / 1024), 256, 0, stream>>>(ctx, ht, G);
}

// Round 6
// 50.552 us; speedup vs baseline: 1.2949x; 1.1363x over previous
//
#include <hip/hip_runtime.h>
#include <stdint.h>

#define T_DIM 8192
#define J_DIM 1024
#define D_DIM 256

typedef __bf16 bf16x8 __attribute__((ext_vector_type(8)));
typedef float f32x4 __attribute__((ext_vector_type(4)));
typedef unsigned short u16x8 __attribute__((ext_vector_type(8)));
typedef unsigned short u16x4 __attribute__((ext_vector_type(4)));

__device__ inline unsigned short f2bf(float x) {
    unsigned u = __builtin_bit_cast(unsigned, x);
    u += 0x7FFFu + ((u >> 16) & 1u);
    return (unsigned short)(u >> 16);
}

// async global->LDS, 16B per lane. LDS dest = wave-uniform base + lane*16 (linear);
// swizzle is applied on the per-lane GLOBAL source address (rule #21).
__device__ inline void gll16(const void* g, void* l) {
    __builtin_amdgcn_global_load_lds(
        (const __attribute__((address_space(1))) unsigned int*)g,
        (__attribute__((address_space(3))) unsigned int*)l, 16, 0, 0);
}

// K0: fused prep. Blocks [0,2048): ctx -> Cm bf16 + cw. [2048,2304): qry -> Qb,QT,qw.
// [2304,2369): zero stats (lsum|rmax|ht = 16640 f32).
__global__ __launch_bounds__(256) void prep_all(const float* __restrict__ ctx,
                                                const float* __restrict__ qry,
                                                const float* __restrict__ w,
                                                unsigned short* __restrict__ Cm,
                                                float* __restrict__ cw,
                                                unsigned short* __restrict__ Qb,
                                                unsigned short* __restrict__ QT,
                                                float* __restrict__ qw,
                                                float* __restrict__ stats) {
    int wid = threadIdx.x >> 6, lane = threadIdx.x & 63;
    if (blockIdx.x >= 2304) {
        int idx = (blockIdx.x - 2304) * 256 + threadIdx.x;
        if (idx < 2 * T_DIM + D_DIM) stats[idx] = 0.0f;
        return;
    }
    if (blockIdx.x < 2048) {
        int t = blockIdx.x * 4 + wid;
        float4 c  = *(const float4*)(ctx + (size_t)t * D_DIM + lane * 4);
        float4 wm = *(const float4*)(w + 2 * D_DIM + lane * 4);
        float4 wc = *(const float4*)(w + lane * 4);
        u16x4 cmv;
        cmv[0] = f2bf(c.x * wm.x);
        cmv[1] = f2bf(c.y * wm.y);
        cmv[2] = f2bf(c.z * wm.z);
        cmv[3] = f2bf(c.w * wm.w);
        *(u16x4*)(Cm + (size_t)t * D_DIM + lane * 4) = cmv;
        float s = c.x * wc.x + c.y * wc.y + c.z * wc.z + c.w * wc.w;
        #pragma unroll
        for (int o = 1; o < 64; o <<= 1) s += __shfl_xor(s, o);
        if (lane == 0) cw[t] = s;
    } else {
        int j = (blockIdx.x - 2048) * 4 + wid;
        float4 c  = *(const float4*)(qry + (size_t)j * D_DIM + lane * 4);
        float4 wq = *(const float4*)(w + D_DIM + lane * 4);
        u16x4 qv;
        qv[0] = f2bf(c.x);
        qv[1] = f2bf(c.y);
        qv[2] = f2bf(c.z);
        qv[3] = f2bf(c.w);
        *(u16x4*)(Qb + (size_t)j * D_DIM + lane * 4) = qv;
        int d0 = lane * 4;
        QT[(size_t)(d0 + 0) * J_DIM + j] = qv[0];
        QT[(size_t)(d0 + 1) * J_DIM + j] = qv[1];
        QT[(size_t)(d0 + 2) * J_DIM + j] = qv[2];
        QT[(size_t)(d0 + 3) * J_DIM + j] = qv[3];
        float s = c.x * wq.x + c.y * wq.y + c.z * wq.z + c.w * wq.w;
        #pragma unroll
        for (int o = 1; o < 64; o <<= 1) s += __shfl_xor(s, o);
        if (lane == 0) qw[j] = s;
    }
}

// K1: P = bf16(exp(Cm @ Qb^T + qw)) + fused row stats (atomics).
// 128x128 tile, BK=64, 8 waves (4m x 2n), global_load_lds staging.
__global__ __launch_bounds__(512) void gemm_s(const unsigned short* __restrict__ Cm,
                                              const unsigned short* __restrict__ Qb,
                                              const float* __restrict__ qw,
                                              unsigned short* __restrict__ P,
                                              float* __restrict__ lsum,
                                              int* __restrict__ rmax) {
    __shared__ unsigned short SH[16384];          // As [128][64] | Bs [128][64]
    __shared__ float statS[2][128];
    __shared__ float statM[2][128];
    unsigned short* As = SH;
    unsigned short* Bs = SH + 8192;
    int tid = threadIdx.x, lane = tid & 63, wv = tid >> 6;
    int wm = wv >> 1, wn = wv & 1;
    int bm = blockIdx.x & 63, bn = blockIdx.x >> 6;
    int cidx = lane & 15, rgrp = lane >> 4;
    int srow8 = lane >> 3;                 // row within 8-row chunk
    int swzc = (lane & 7) ^ srow8;         // inverse-swizzled source chunk
    f32x4 acc[2][4] = {};

    const unsigned short* Asrc = Cm + (size_t)(bm * 128 + srow8) * 256 + (swzc << 3);
    const unsigned short* Bsrc = Qb + (size_t)(bn * 128 + srow8) * 256 + (swzc << 3);

    for (int k0 = 0; k0 < 256; k0 += 64) {
        if (k0) __syncthreads();
        #pragma unroll
        for (int i = 0; i < 2; ++i) {
            int ci = wv * 2 + i;
            gll16(Asrc + (size_t)(ci * 8) * 256 + k0, As + ci * 512);
            gll16(Bsrc + (size_t)(ci * 8) * 256 + k0, Bs + ci * 512);
        }
        __syncthreads();
        #pragma unroll
        for (int ks = 0; ks < 2; ++ks) {
            int klo = ks * 4 + rgrp;
            bf16x8 af[2], bfr[4];
            #pragma unroll
            for (int m = 0; m < 2; ++m) {
                int ra = wm * 32 + m * 16 + cidx;
                af[m] = __builtin_bit_cast(bf16x8,
                        *(const u16x8*)(As + ra * 64 + ((klo ^ (ra & 7)) << 3)));
            }
            #pragma unroll
            for (int n = 0; n < 4; ++n) {
                int rb = wn * 64 + n * 16 + cidx;
                bfr[n] = __builtin_bit_cast(bf16x8,
                        *(const u16x8*)(Bs + rb * 64 + ((klo ^ (rb & 7)) << 3)));
            }
            #pragma unroll
            for (int m = 0; m < 2; ++m)
                #pragma unroll
                for (int n = 0; n < 4; ++n)
                    acc[m][n] = __builtin_amdgcn_mfma_f32_16x16x32_bf16(af[m], bfr[n], acc[m][n], 0, 0, 0);
        }
    }

    // exp + per-row stats
    float qwv[4];
    #pragma unroll
    for (int n = 0; n < 4; ++n) qwv[n] = qw[bn * 128 + wn * 64 + n * 16 + cidx];
    #pragma unroll
    for (int m = 0; m < 2; ++m) {
        #pragma unroll
        for (int rg = 0; rg < 4; ++rg) {
            float s = 0.f, mx = 0.f;
            #pragma unroll
            for (int n = 0; n < 4; ++n) {
                float p = __expf(acc[m][n][rg] + qwv[n]);
                acc[m][n][rg] = p;
                s += p;
                mx = fmaxf(mx, p);
            }
            #pragma unroll
            for (int o = 1; o < 16; o <<= 1) {
                s += __shfl_xor(s, o);
                mx = fmaxf(mx, __shfl_xor(mx, o));
            }
            if (cidx == 0) {
                int row = wm * 32 + m * 16 + rgrp * 4 + rg;
                statS[wn][row] = s;
                statM[wn][row] = mx;
            }
        }
    }
    __syncthreads();
    if (tid < 128) {
        atomicAdd(lsum + bm * 128 + tid, statS[0][tid] + statS[1][tid]);
        atomicMax(rmax + bm * 128 + tid,
                  __float_as_int(fmaxf(statM[0][tid], statM[1][tid])));
    }

    // restage P tile (swizzled) + coalesced u16x8 stores
    #pragma unroll
    for (int m = 0; m < 2; ++m)
        #pragma unroll
        for (int n = 0; n < 4; ++n)
            #pragma unroll
            for (int rg = 0; rg < 4; ++rg) {
                int row = wm * 32 + m * 16 + rgrp * 4 + rg;
                int col = wn * 64 + n * 16 + cidx;
                SH[row * 128 + (((col >> 3) ^ (row & 7)) << 3) + (col & 7)] = f2bf(acc[m][n][rg]);
            }
    __syncthreads();
    #pragma unroll
    for (int i = 0; i < 4; ++i) {
        int r = i * 32 + (tid >> 4);
        int c8 = tid & 15;
        u16x8 v = *(const u16x8*)(SH + r * 128 + ((c8 ^ (r & 7)) << 3));
        *(u16x8*)(P + (size_t)(bm * 128 + r) * J_DIM + bn * 128 + c8 * 8) = v;
    }
}

// K2: b = log(rmax)+cw, ht[d] += sum_t b*ctx. 128 blocks x 64 rows.
__global__ __launch_bounds__(256) void hb_kernel(const float* __restrict__ rmaxf,
                                                 const float* __restrict__ cw,
                                                 const float* __restrict__ ctx,
                                                 float* __restrict__ ht) {
    __shared__ float bsh[64];
    int tid = threadIdx.x;
    int t0b = blockIdx.x * 64;
    if (tid < 64) bsh[tid] = __logf(rmaxf[t0b + tid]) + cw[t0b + tid];
    __syncthreads();
    float pb = 0.f;
    #pragma unroll 8
    for (int r = 0; r < 64; ++r)
        pb += bsh[r] * ctx[(size_t)(t0b + r) * D_DIM + tid];
    atomicAdd(ht + tid, pb);
}

// K3: O = P @ query (QT rows = B^T); epilogue writes all 4 G col-blocks.
// 128x64 tile, BK=64, 8 waves (4m x 2n), global_load_lds staging.
__global__ __launch_bounds__(512) void gemm_o(const unsigned short* __restrict__ P,
                                              const unsigned short* __restrict__ QT,
                                              const float* __restrict__ lsum,
                                              const float* __restrict__ ht,
                                              const float* __restrict__ ctx,
                                              float* __restrict__ G) {
    __shared__ unsigned short As[8192];    // [128][64]
    __shared__ unsigned short Bs[4096];    // [64][64]
    int tid = threadIdx.x, lane = tid & 63, wv = tid >> 6;
    int wm = wv >> 1, wn = wv & 1;
    int bm = blockIdx.x & 63, bn = blockIdx.x >> 6;
    int cidx = lane & 15, rgrp = lane >> 4;
    int srow8 = lane >> 3;
    int swzc = (lane & 7) ^ srow8;
    f32x4 acc[2][2] = {};

    const unsigned short* Ap = P  + (size_t)(bm * 128 + srow8) * J_DIM + (swzc << 3);
    const unsigned short* Bp = QT + (size_t)(bn * 64  + srow8) * J_DIM + (swzc << 3);

    for (int k0 = 0; k0 < 1024; k0 += 64) {
        if (k0) __syncthreads();
        #pragma unroll
        for (int i = 0; i < 2; ++i) {
            int ci = wv * 2 + i;
            gll16(Ap + (size_t)(ci * 8) * J_DIM + k0, As + ci * 512);
        }
        gll16(Bp + (size_t)(wv * 8) * J_DIM + k0, Bs + wv * 512);
        __syncthreads();
        #pragma unroll
        for (int ks = 0; ks < 2; ++ks) {
            int klo = ks * 4 + rgrp;
            bf16x8 af[2], bfr[2];
            #pragma unroll
            for (int m = 0; m < 2; ++m) {
                int ra = wm * 32 + m * 16 + cidx;
                af[m] = __builtin_bit_cast(bf16x8,
                        *(const u16x8*)(As + ra * 64 + ((klo ^ (ra & 7)) << 3)));
            }
            #pragma unroll
            for (int n = 0; n < 2; ++n) {
                int rb = wn * 32 + n * 16 + cidx;
                bfr[n] = __builtin_bit_cast(bf16x8,
                        *(const u16x8*)(Bs + rb * 64 + ((klo ^ (rb & 7)) << 3)));
            }
            #pragma unroll
            for (int m = 0; m < 2; ++m)
                #pragma unroll
                for (int n = 0; n < 2; ++n)
                    acc[m][n] = __builtin_amdgcn_mfma_f32_16x16x32_bf16(af[m], bfr[n], acc[m][n], 0, 0, 0);
        }
    }

    float htv[2];
    #pragma unroll
    for (int n = 0; n < 2; ++n) htv[n] = ht[bn * 64 + wn * 32 + n * 16 + cidx];
    #pragma unroll
    for (int m = 0; m < 2; ++m) {
        #pragma unroll
        for (int rg = 0; rg < 4; ++rg) {
            int t = bm * 128 + wm * 32 + m * 16 + rgrp * 4 + rg;
            float linv = 1.0f / lsum[t];
            float* gr = G + (size_t)t * 1024;
            #pragma unroll
            for (int n = 0; n < 2; ++n) {
                int d = bn * 64 + wn * 32 + n * 16 + cidx;
                float val = acc[m][n][rg] * linv;
                float c = ctx[(size_t)t * D_DIM + d];
                gr[d]       = c;
                gr[256 + d] = val;
                gr[512 + d] = c * val;
                gr[768 + d] = c * htv[n];
            }
        }
    }
}

extern "C" void kernel_launch(void* const* d_in, const int* in_sizes, int n_in,
                              void* d_out, int out_size, void* d_ws, size_t ws_size,
                              hipStream_t stream) {
    (void)in_sizes; (void)n_in; (void)out_size; (void)ws_size;
    const float* ctx = (const float*)d_in[0];
    const float* qry = (const float*)d_in[1];
    const float* w   = (const float*)d_in[2];
    float* G = (float*)d_out;
    char* ws = (char*)d_ws;

    constexpr size_t OFF_P  = 0;                                   // 16 MiB
    constexpr size_t OFF_CM = OFF_P  + (size_t)T_DIM * J_DIM * 2;  // 4 MiB
    constexpr size_t OFF_QB = OFF_CM + (size_t)T_DIM * D_DIM * 2;
    constexpr size_t OFF_QT = OFF_QB + (size_t)J_DIM * D_DIM * 2;
    constexpr size_t OFF_CW = OFF_QT + (size_t)D_DIM * J_DIM * 2;
    constexpr size_t OFF_QW = OFF_CW + (size_t)T_DIM * 4;
    constexpr size_t OFF_ST = OFF_QW + (size_t)J_DIM * 4;

    unsigned short* P  = (unsigned short*)(ws + OFF_P);
    unsigned short* Cm = (unsigned short*)(ws + OFF_CM);
    unsigned short* Qb = (unsigned short*)(ws + OFF_QB);
    unsigned short* QT = (unsigned short*)(ws + OFF_QT);
    float* cw    = (float*)(ws + OFF_CW);
    float* qw    = (float*)(ws + OFF_QW);
    float* stats = (float*)(ws + OFF_ST);
    float* lsum  = stats;                 // 8192
    float* rmax  = stats + T_DIM;         // 8192 (float bits via int atomicMax)
    float* ht    = stats + 2 * T_DIM;     // 256

    prep_all<<<dim3(2369), 256, 0, stream>>>(ctx, qry, w, Cm, cw, Qb, QT, qw, stats);
    gemm_s<<<dim3(512), 512, 0, stream>>>(Cm, Qb, qw, P, lsum, (int*)rmax);
    hb_kernel<<<dim3(128), 256, 0, stream>>>(rmax, cw, ctx, ht);
    gemm_o<<<dim3(256), 512, 0, stream>>>(P, QT, lsum, ht, ctx, G);
}